// Round 4
// baseline (262.886 us; speedup 1.0000x reference)
//
#include <hip/hip_runtime.h>
#include <stdint.h>

#define BB 16
#define SS 4096
#define DD 1024
#define NROWS (BB * SS)          // 65536
#define F4_PER_ROW (DD / 4)      // 256 float4 per (b,t) row
#define GRID_APPLY 2048          // compile-time stride -> full unroll, 32 iters
#define ITERS (NROWS / GRID_APPLY)  // 32

typedef float __attribute__((ext_vector_type(4))) f4raw;

// ws layout (ints): ws[0..15] = per-batch lengths, ws[16] = isBool flag

// grid = 16 blocks x 256. Vectorized uint4 loads throughout.
//  1) dtype detect: int32 {0,1} storage has all upper-3 bytes of each dword == 0;
//     1-byte bool storage (random prefix masks) has nonzero upper bytes.
//     First 64KB is in-bounds under both layouts (bool: 64KB total, int32: 256KB).
//  2) per-batch length = count of nonzero mask elements.
__global__ __launch_bounds__(256) void prep_kernel(const uint8_t* __restrict__ m8,
                                                   int* __restrict__ ws) {
    const int b = blockIdx.x;     // 0..15
    const int tid = threadIdx.x;  // 0..255
    __shared__ int sh[256];
    const uint4* v16 = (const uint4*)m8;

    uint32_t odd = 0;
    #pragma unroll
    for (int k = 0; k < 16; ++k) {
        uint4 v = v16[k * 256 + tid];
        odd |= (v.x | v.y | v.z | v.w) & 0xFFFFFF00u;
    }
    sh[tid] = (odd != 0);
    __syncthreads();
    for (int s = 128; s > 0; s >>= 1) {
        if (tid < s) sh[tid] |= sh[tid + s];
        __syncthreads();
    }
    const int isBool = sh[0];
    __syncthreads();

    int cnt = 0;
    if (isBool) {
        uint4 v = v16[b * 256 + tid];
        uint32_t w[4] = {v.x, v.y, v.z, v.w};
        #pragma unroll
        for (int j = 0; j < 4; ++j) {
            cnt += ((w[j] & 0x000000FFu) != 0) + ((w[j] & 0x0000FF00u) != 0)
                 + ((w[j] & 0x00FF0000u) != 0) + ((w[j] & 0xFF000000u) != 0);
        }
    } else {
        const uint4* row = (const uint4*)((const int*)m8 + (size_t)b * SS);
        #pragma unroll
        for (int k = 0; k < 4; ++k) {
            uint4 v = row[k * 256 + tid];
            cnt += (v.x != 0) + (v.y != 0) + (v.z != 0) + (v.w != 0);
        }
    }
    sh[tid] = cnt;
    __syncthreads();
    for (int s = 128; s > 0; s >>= 1) {
        if (tid < s) sh[tid] += sh[tid + s];
        __syncthreads();
    }
    if (tid == 0) {
        ws[b] = sh[0];
        if (b == 0) ws[16] = isBool;
    }
}

// grid = 2048 blocks x 256, row = blockIdx + k*2048 (round-2 winning layout:
// the 2048 blocks sweep one contiguous ~8MB output window per iteration).
// All 32 mask decisions are resolved UPFRONT (wave-uniform scalar loads,
// issued back-to-back) so the per-iteration chain is just cond-load + NT store.
__global__ __launch_bounds__(256) void apply_kernel(const float4* __restrict__ x,
                                                    const uint8_t* __restrict__ m8,
                                                    const int* __restrict__ ws,
                                                    float4* __restrict__ out) {
    const int isBool = ws[16];
    const int* m32 = (const int*)m8;
    const float4 z = make_float4(0.f, 0.f, 0.f, 0.f);

    // Preload per-iteration on/off decisions (all wave-uniform).
    bool on[ITERS];
    #pragma unroll
    for (int k = 0; k < ITERS; ++k) {
        const int row = blockIdx.x + k * GRID_APPLY;
        const int t = row & (SS - 1);
        const int b = row >> 12;
        const int m = isBool ? (int)m8[row] : m32[row];
        on[k] = (m != 0) && (t < ws[b]);
    }

    #pragma unroll 4
    for (int k = 0; k < ITERS; ++k) {
        const int row = blockIdx.x + k * GRID_APPLY;
        const size_t idx = (size_t)row * F4_PER_ROW + threadIdx.x;
        float4 v = z;
        if (on[k]) v = x[idx];
        __builtin_nontemporal_store(*(const f4raw*)&v, (f4raw*)&out[idx]);
    }
}

extern "C" void kernel_launch(void* const* d_in, const int* in_sizes, int n_in,
                              void* d_out, int out_size, void* d_ws, size_t ws_size,
                              hipStream_t stream) {
    const float*   x    = (const float*)d_in[0];
    const uint8_t* mask = (const uint8_t*)d_in[1];
    int* ws = (int*)d_ws;

    prep_kernel<<<BB, 256, 0, stream>>>(mask, ws);
    apply_kernel<<<GRID_APPLY, 256, 0, stream>>>((const float4*)x, mask, ws, (float4*)d_out);
}

// Round 5
// 59.620 us; speedup vs baseline: 4.4093x; 4.4093x over previous
//
#include <hip/hip_runtime.h>
#include <stdint.h>

#define BB 16
#define SS 4096
#define DD 1024
#define NROWS (BB * SS)          // 65536
#define F4_PER_ROW (DD / 4)      // 256 float4 per (b,t) row
#define NVEC  ((size_t)NROWS * F4_PER_ROW)  // 16,777,216 float4 elements

typedef float __attribute__((ext_vector_type(4))) f4raw;

// ws layout (ints): ws[0..15] = per-batch lengths, ws[16] = isBool flag

// grid = 16 blocks x 256. Vectorized uint4 loads throughout.
//  1) dtype detect: int32 {0,1} storage has all upper-3 bytes of each dword == 0;
//     1-byte bool storage (random prefix masks) has nonzero upper bytes.
//     First 64KB is in-bounds under both layouts (bool: 64KB total, int32: 256KB).
//  2) per-batch length = count of nonzero mask elements.
__global__ __launch_bounds__(256) void prep_kernel(const uint8_t* __restrict__ m8,
                                                   int* __restrict__ ws) {
    const int b = blockIdx.x;     // 0..15
    const int tid = threadIdx.x;  // 0..255
    __shared__ int sh[256];
    const uint4* v16 = (const uint4*)m8;

    uint32_t odd = 0;
    #pragma unroll
    for (int k = 0; k < 16; ++k) {
        uint4 v = v16[k * 256 + tid];
        odd |= (v.x | v.y | v.z | v.w) & 0xFFFFFF00u;
    }
    sh[tid] = (odd != 0);
    __syncthreads();
    for (int s = 128; s > 0; s >>= 1) {
        if (tid < s) sh[tid] |= sh[tid + s];
        __syncthreads();
    }
    const int isBool = sh[0];
    __syncthreads();

    int cnt = 0;
    if (isBool) {
        uint4 v = v16[b * 256 + tid];
        uint32_t w[4] = {v.x, v.y, v.z, v.w};
        #pragma unroll
        for (int j = 0; j < 4; ++j) {
            cnt += ((w[j] & 0x000000FFu) != 0) + ((w[j] & 0x0000FF00u) != 0)
                 + ((w[j] & 0x00FF0000u) != 0) + ((w[j] & 0xFF000000u) != 0);
        }
    } else {
        const uint4* row = (const uint4*)((const int*)m8 + (size_t)b * SS);
        #pragma unroll
        for (int k = 0; k < 4; ++k) {
            uint4 v = row[k * 256 + tid];
            cnt += (v.x != 0) + (v.y != 0) + (v.z != 0) + (v.w != 0);
        }
    }
    sh[tid] = cnt;
    __syncthreads();
    for (int s = 128; s > 0; s >>= 1) {
        if (tid < s) sh[tid] += sh[tid + s];
        __syncthreads();
    }
    if (tid == 0) {
        ws[b] = sh[0];
        if (b == 0) ws[16] = isBool;
    }
}

// grid = 2048 blocks x 256. Round-2 proven layout: grid-stride over float4
// elements — the 2048 blocks sweep one contiguous ~8MB output window per
// iteration (channel-balanced write wavefront). Mask load is block-uniform
// (L1 broadcast), keep/zero branch is wave-uniform, x load skipped for zero
// rows. NT stores keep the 268MB output stream from evicting x out of LLC.
__global__ __launch_bounds__(256) void apply_kernel(const float4* __restrict__ x,
                                                    const uint8_t* __restrict__ m8,
                                                    const int* __restrict__ ws,
                                                    float4* __restrict__ out) {
    __shared__ int len_sh[BB];
    __shared__ int isBool_sh;
    if (threadIdx.x < BB) len_sh[threadIdx.x] = ws[threadIdx.x];
    if (threadIdx.x == 0) isBool_sh = ws[16];
    __syncthreads();
    const int isBool = isBool_sh;
    const int* m32 = (const int*)m8;
    const float4 z = make_float4(0.f, 0.f, 0.f, 0.f);

    const size_t stride = (size_t)gridDim.x * blockDim.x;
    for (size_t i = (size_t)blockIdx.x * blockDim.x + threadIdx.x; i < NVEC; i += stride) {
        const int row = (int)(i >> 8);      // F4_PER_ROW = 256
        const int t   = row & (SS - 1);
        const int b   = row >> 12;          // SS = 4096
        const int m   = isBool ? (int)m8[row] : m32[row];
        const bool on = (m != 0) && (t < len_sh[b]);
        float4 v = z;
        if (on) v = x[i];
        __builtin_nontemporal_store(*(const f4raw*)&v, (f4raw*)&out[i]);
    }
}

extern "C" void kernel_launch(void* const* d_in, const int* in_sizes, int n_in,
                              void* d_out, int out_size, void* d_ws, size_t ws_size,
                              hipStream_t stream) {
    const float*   x    = (const float*)d_in[0];
    const uint8_t* mask = (const uint8_t*)d_in[1];
    int* ws = (int*)d_ws;

    prep_kernel<<<BB, 256, 0, stream>>>(mask, ws);
    apply_kernel<<<2048, 256, 0, stream>>>((const float4*)x, mask, ws, (float4*)d_out);
}